// Round 1
// 562.781 us; speedup vs baseline: 1.1138x; 1.1138x over previous
//
#include <hip/hip_runtime.h>
#include <cstdint>
#include <cstddef>

// LoRALinear: out[T,M] = x[T,N] @ (W + A@B^T)^T + b   (alpha = 8/8 = 1)
// T=8192, M=4096, N=4096, RANK=8, fp32 in/out.
//
// Round-4:
//  * Fold delta_W into Wh:  Wh = f16(W + A@B^T)  -> kills fuse_x's dot phase,
//    the xB buffer, and the LoRA epilogue. Prep is now two pure streaming passes.
//  * GEMM rewritten as the 256x256 8-phase counted-vmcnt template (BK=64,
//    8 waves, 128 KiB double-buffered LDS, XOR-swizzled LDS reads, setprio
//    around MFMA clusters). vmcnt(4) checkpoints before the ph3/ph7 barriers;
//    never drained to 0 in the main loop.

#define T_DIM 8192
#define M_DIM 4096
#define N_DIM 4096
#define RANK  8

typedef _Float16 f16x8 __attribute__((ext_vector_type(8)));
typedef float    f32x4 __attribute__((ext_vector_type(4)));

// ---------------------------------------------------------------- pass 1
// pure fp32 -> f16 streaming cast (x)
__global__ __launch_bounds__(256)
void cast_x(const float* __restrict__ src, _Float16* __restrict__ dst) {
    size_t i = ((size_t)blockIdx.x * blockDim.x + threadIdx.x) * 8;
    f32x4 v0 = *(const f32x4*)(src + i);
    f32x4 v1 = *(const f32x4*)(src + i + 4);
    f16x8 o;
#pragma unroll
    for (int k = 0; k < 4; ++k) { o[k] = (_Float16)v0[k]; o[4 + k] = (_Float16)v1[k]; }
    *(f16x8*)(dst + i) = o;
}

// ---------------------------------------------------------------- pass 2
// Wh[m][n] = f16( W[m][n] + dot(A[m,:], B[n,:]) )
// thread owns 8 consecutive n at fixed m: W loads 32B contiguous, B rows
// n0..n0+7 are 256B contiguous ([N][8] row-major), A row wave-uniform.
__global__ __launch_bounds__(256)
void prep_w(const float* __restrict__ W, const float* __restrict__ A,
            const float* __restrict__ B, _Float16* __restrict__ Wh) {
    const size_t c = (size_t)blockIdx.x * 256 + threadIdx.x;
    const int m  = (int)(c >> 9);          // 512 chunks of 8 per row
    const int n0 = (int)(c & 511) << 3;
    f32x4 a0 = *(const f32x4*)(A + (size_t)m * RANK);
    f32x4 a1 = *(const f32x4*)(A + (size_t)m * RANK + 4);
    const float* wp = W + (size_t)m * N_DIM + n0;
    f32x4 w0 = *(const f32x4*)wp;
    f32x4 w1 = *(const f32x4*)(wp + 4);
    f16x8 o;
#pragma unroll
    for (int k = 0; k < 8; ++k) {
        const float* Bn = B + (size_t)(n0 + k) * RANK;
        f32x4 b0 = *(const f32x4*)Bn;
        f32x4 b1 = *(const f32x4*)(Bn + 4);
        float d = a0[0]*b0[0] + a0[1]*b0[1] + a0[2]*b0[2] + a0[3]*b0[3]
                + a1[0]*b1[0] + a1[1]*b1[1] + a1[2]*b1[2] + a1[3]*b1[3];
        float wv = (k < 4) ? w0[k] : w1[k - 4];
        o[k] = (_Float16)(wv + d);
    }
    *(f16x8*)(Wh + (size_t)m * N_DIM + n0) = o;
}

// ---------------------------------------------------------------- GEMM
__device__ static inline void gld16(const _Float16* g, _Float16* l) {
    __builtin_amdgcn_global_load_lds(
        (const __attribute__((address_space(1))) unsigned int*)g,
        (__attribute__((address_space(3))) unsigned int*)l, 16, 0, 0);
}

// 256x256 tile, BK=64, 512 threads = 8 waves (2M x 4N), per-wave C = 128x64.
// LDS: double-buffered [256][64] f16 tiles for A and B = 128 KiB.
// Logical 16B chunk l of row R stored at phys chunk l ^ (R&7)  (involution;
// source address pre-swizzled so global_load_lds' linear dest works).
// B rows permuted in LDS: phys p = h*128 + wcn*32 + s  <->  W row wcn*64+h*32+s
// so qn-halves are LDS-contiguous for staging.
__global__ __launch_bounds__(512, 2)
void gemm256(const _Float16* __restrict__ Xh, const _Float16* __restrict__ Wh,
             const float* __restrict__ bias, float* __restrict__ out) {
    __shared__ __align__(16) _Float16 lA[2][256 * 64];
    __shared__ __align__(16) _Float16 lB[2][256 * 64];

    const int tid  = threadIdx.x;
    const int lane = tid & 63;
    const int fr   = lane & 15;
    const int fq   = lane >> 4;
    const int w    = tid >> 6;
    const int wr   = w >> 2;      // 0..1  (M)
    const int wcn  = w & 3;       // 0..3  (N)

    const size_t rowX0 = (size_t)blockIdx.y * 256;
    const size_t rowW0 = (size_t)blockIdx.x * 256;

    // staging source addressing (per-thread, kt-invariant)
    const int srow = tid >> 3;                                // 0..63
    const int scol = ((tid & 7) * 8) ^ ((srow & 7) * 8);      // pre-swizzled col
    const _Float16* sA = Xh + (rowX0 + srow) * N_DIM + scol;
    const _Float16* sBp[4];
#pragma unroll
    for (int cb = 0; cb < 4; ++cb) {
        const int p = cb * 64 + srow;
        const int wrow = ((p >> 5) & 3) * 64 + ((p >> 7) & 1) * 32 + (p & 31);
        sBp[cb] = Wh + (rowW0 + wrow) * N_DIM + scol;
    }

    // fragment-read swizzled column (f16 units); ksub=1 flips bit 5
    const int kc0 = (fq * 8) ^ ((fr & 7) * 8);

    f32x4 acc[8][4] = {};
    f16x8 af[4][2], bf[4][2];

#define STAGE_A(b, rb, kt) gld16(sA + (size_t)(rb) * N_DIM + (kt) * 64, \
                                 &lA[b][(rb) * 64 + tid * 8])
#define STAGE_B(b, cb, kt) gld16(sBp[cb] + (size_t)(kt) * 64, \
                                 &lB[b][(cb) * 4096 + tid * 8])

#define LDA(b, qm) do { _Pragma("unroll") \
    for (int ii = 0; ii < 4; ++ii) { \
        const int ro_ = (wr * 128 + (qm) * 64 + ii * 16 + fr) * 64; \
        af[ii][0] = *(const f16x8*)&lA[b][ro_ + kc0]; \
        af[ii][1] = *(const f16x8*)&lA[b][ro_ + (kc0 ^ 32)]; } } while (0)

#define LDB(b, qn) do { _Pragma("unroll") \
    for (int jj = 0; jj < 2; ++jj) { \
        const int ro_ = ((qn) * 128 + wcn * 32 + jj * 16 + fr) * 64; \
        bf[(qn) * 2 + jj][0] = *(const f16x8*)&lB[b][ro_ + kc0]; \
        bf[(qn) * 2 + jj][1] = *(const f16x8*)&lB[b][ro_ + (kc0 ^ 32)]; } } while (0)

#define MMA(qm, qn) do { __builtin_amdgcn_s_setprio(1); \
    _Pragma("unroll") for (int ii = 0; ii < 4; ++ii) \
    _Pragma("unroll") for (int jj = 0; jj < 2; ++jj) { \
        acc[(qm)*4+ii][(qn)*2+jj] = __builtin_amdgcn_mfma_f32_16x16x32_f16( \
            af[ii][0], bf[(qn)*2+jj][0], acc[(qm)*4+ii][(qn)*2+jj], 0, 0, 0); \
        acc[(qm)*4+ii][(qn)*2+jj] = __builtin_amdgcn_mfma_f32_16x16x32_f16( \
            af[ii][1], bf[(qn)*2+jj][1], acc[(qm)*4+ii][(qn)*2+jj], 0, 0, 0); } \
    __builtin_amdgcn_s_setprio(0); \
    __builtin_amdgcn_sched_barrier(0); } while (0)

#define BAR asm volatile("s_barrier" ::: "memory")
#define VW4 asm volatile("s_waitcnt vmcnt(4)" ::: "memory")
#define VW0 asm volatile("s_waitcnt vmcnt(0)" ::: "memory")

    // ---- prologue: kt0 full -> buf0; kt1 A-q0 + B-h0 -> buf1 (12 loads)
    STAGE_A(0, 0, 0);   STAGE_A(0, 128, 0);  STAGE_B(0, 0, 0);  STAGE_B(0, 1, 0);
    STAGE_A(0, 64, 0);  STAGE_A(0, 192, 0);  STAGE_B(0, 2, 0);  STAGE_B(0, 3, 0);
    STAGE_A(1, 0, 1);   STAGE_A(1, 128, 1);  STAGE_B(1, 0, 1);  STAGE_B(1, 1, 1);
    VW4; BAR;   // kt0 complete; kt1 partial in flight

    // ---- main loop: iter n computes kt 2n (buf0) and 2n+1 (buf1)
#pragma unroll 1
    for (int n = 0; n < (N_DIM / 128) - 1; ++n) {
        const int ko  = 2 * n + 1;
        const int kne = 2 * n + 2;
        const int kno = 2 * n + 3;
        // ph0
        LDA(0, 0); LDB(0, 0);
        STAGE_A(1, 64, ko); STAGE_A(1, 192, ko); STAGE_B(1, 2, ko); STAGE_B(1, 3, ko);
        BAR; MMA(0, 0); BAR;
        // ph1
        LDB(0, 1);
        BAR; MMA(0, 1); BAR;
        // ph2
        LDA(0, 1); STAGE_A(0, 0, kne); STAGE_A(0, 128, kne);
        BAR; MMA(1, 0); BAR;
        // ph3
        STAGE_B(0, 0, kne); STAGE_B(0, 1, kne);
        BAR; MMA(1, 1); VW4; BAR;   // confirms kt_odd fully staged
        // ph4
        LDA(1, 0); LDB(1, 0); STAGE_A(0, 64, kne); STAGE_A(0, 192, kne);
        BAR; MMA(0, 0); BAR;
        // ph5
        LDB(1, 1); STAGE_B(0, 2, kne); STAGE_B(0, 3, kne);
        BAR; MMA(0, 1); BAR;
        // ph6
        LDA(1, 1); STAGE_A(1, 0, kno); STAGE_A(1, 128, kno);
        BAR; MMA(1, 0); BAR;
        // ph7
        STAGE_B(1, 0, kno); STAGE_B(1, 1, kno);
        BAR; MMA(1, 1); VW4; BAR;   // confirms kt_next_even fully staged
    }

    // ---- final iteration (kt 62 in buf0, kt 63 in buf1): no new prefetch
    {
        const int ko = N_DIM / 64 - 1;   // 63
        LDA(0, 0); LDB(0, 0);
        STAGE_A(1, 64, ko); STAGE_A(1, 192, ko); STAGE_B(1, 2, ko); STAGE_B(1, 3, ko);
        BAR; MMA(0, 0); BAR;
        LDB(0, 1);
        BAR; MMA(0, 1); BAR;
        LDA(0, 1);
        BAR; MMA(1, 0); BAR;
        BAR; MMA(1, 1); VW0; BAR;        // drain: kt63 complete
        LDA(1, 0); LDB(1, 0);
        BAR; MMA(0, 0); BAR;
        LDB(1, 1);
        BAR; MMA(0, 1); BAR;
        LDA(1, 1);
        BAR; MMA(1, 0); BAR;
        MMA(1, 1);
    }

    // ---- epilogue: C row = fq*4+reg (token), col = fr (out feature); + bias
    const int crow0 = (int)rowX0 + wr * 128;
    const int ccol0 = (int)rowW0 + wcn * 64;
    float bv[4];
#pragma unroll
    for (int j = 0; j < 4; ++j) bv[j] = bias[ccol0 + j * 16 + fr];
#pragma unroll
    for (int i = 0; i < 8; ++i) {
#pragma unroll
        for (int r = 0; r < 4; ++r) {
            const size_t row = (size_t)(crow0 + i * 16 + fq * 4 + r);
#pragma unroll
            for (int j = 0; j < 4; ++j)
                out[row * M_DIM + ccol0 + j * 16 + fr] = acc[i][j][r] + bv[j];
        }
    }
#undef STAGE_A
#undef STAGE_B
#undef LDA
#undef LDB
#undef MMA
#undef BAR
#undef VW4
#undef VW0
}

// ---------------------------------------------------------------- launch
extern "C" void kernel_launch(void* const* d_in, const int* in_sizes, int n_in,
                              void* d_out, int out_size, void* d_ws, size_t ws_size,
                              hipStream_t stream) {
    const float* x = (const float*)d_in[0];
    const float* W = (const float*)d_in[1];
    const float* b = (const float*)d_in[2];
    const float* A = (const float*)d_in[3];
    const float* B = (const float*)d_in[4];
    float* out = (float*)d_out;

    // ws: [Wh f16 32MB][Xh f16 64MB]
    _Float16* Wh = (_Float16*)d_ws;
    _Float16* Xh = (_Float16*)((char*)d_ws + (size_t)M_DIM * N_DIM * 2);

    cast_x<<<((size_t)T_DIM * N_DIM / 8) / 256, 256, 0, stream>>>(x, Xh);
    prep_w<<<((size_t)M_DIM * N_DIM / 8) / 256, 256, 0, stream>>>(W, A, B, Wh);

    dim3 grid(M_DIM / 256, T_DIM / 256);
    gemm256<<<grid, dim3(512, 1, 1), 0, stream>>>(Xh, Wh, b, out);
}